// Round 4
// baseline (392.712 us; speedup 1.0000x reference)
//
#include <hip/hip_runtime.h>

// Fused 5-iteration Jacobi, cross-stencil, B=16, H=W=1024 fp32.
// R8: h=8 decomposition. Each thread owns an 8-row x 4-col octet held
// entirely in VGPRs; only octet-boundary rows {0,1,6,7} are exchanged via a
// ping-pong LDS buffer (rows 2-5 never touch LDS). Halves LDS b128 traffic
// per point vs the h=4 quad scheme (R7: all rows were boundary rows) and
// halves thread count (per-thread overhead amortized over 32 pts).
//  - Tile 128x68, compute rows 2..65 (8 octets), output 104x44, grid
//    10x24x16 = 3840 blocks = EXACTLY 15 blocks/CU (no imbalance tail).
//  - LDS: 2 x (8 oct x 4 rows x 128) ping-pong = 32 KiB + 4 frozen halo rows
//    (tile rows 0,1,66,67) = 34 KiB -> 4 blocks/CU, 256-thread barriers.
//  - x-halos via __shfl from neighbor lanes (unchanged from R7); y-halos:
//    2 b128 reads up + 2 down per sweep from the exchange buffer.
//  - Rolling register window: o_j overwrites f_{j-2} after its last use, so
//    the sweep needs ~2-3 o-temps live, keeping VGPR under the 128 cap of
//    __launch_bounds__(256,4). R6 lesson: spill shows up as FETCH explosion.
//  - Final sweep stores straight from registers; XCD-chunked swizzle
//    (bijective, 3840 = 8*480) kept for L2 locality.
// Cone safety (unchanged arguments): stored rows 12..55 <- rows 2..65 (all
// computed); stored cols 12..115 <- cols 2..125; shuffle-wrap garbage cols
// {0,1,126,127} and frozen rows {0,1,66,67} stay outside the 5-sweep cone.

#define HH 1024
#define WW 1024
#define NB 16
#define GX 10
#define GY 24              // ceil(1024/44)
#define TX 104
#define TY 44
#define HALO 12
#define TWX 128            // LDS row width == stride (floats), %32 banks == 0
#define NOCT 8
#define NTHREADS 256
#define NITER 5
#define NBLK (GX * GY * NB)   // 3840
#define NXCD 8
#define CHUNK (NBLK / NXCD)   // 480 (exact -> bijective)
#define XB (NOCT * 4 * TWX)   // floats per exchange buffer (4096)

struct Coef { float sH1, sH2, sW1, sW2; };

__device__ __forceinline__ float4 ld4(const float* p) { return *(const float4*)p; }
__device__ __forceinline__ void st4(float* p, float4 v) { *(float4*)p = v; }

// clamp-replicate float4 load (used for all global tile/rhs loads; one-time)
__device__ __forceinline__ float4 ld4g(const float* img, int gy, int gxl) {
    gy = gy < 0 ? 0 : (gy > HH - 1 ? HH - 1 : gy);
    const float* row = img + (size_t)gy * WW;
    if (gxl >= 0 && gxl <= WW - 4) return ld4(row + gxl);
    int xa = gxl + 0; xa = xa < 0 ? 0 : (xa > WW - 1 ? WW - 1 : xa);
    int xb = gxl + 1; xb = xb < 0 ? 0 : (xb > WW - 1 ? WW - 1 : xb);
    int xc = gxl + 2; xc = xc < 0 ? 0 : (xc > WW - 1 ? WW - 1 : xc);
    int xd = gxl + 3; xd = xd < 0 ? 0 : (xd > WW - 1 ? WW - 1 : xd);
    return make_float4(row[xa], row[xb], row[xc], row[xd]);
}

template <bool EDGE>
__device__ __forceinline__ float4 row_update(
    const float4 a2, const float4 a1, const float4 ct, const float4 b1, const float4 b2,
    const float4 rv, const Coef cf, const int lm, const int lp,
    const int gy, const int gx0)
{
    // x-halo from neighbor lanes' center-row registers (ds_bpermute crossbar)
    const float hmx = __shfl(ct.z, lm, 64);
    const float hmy = __shfl(ct.w, lm, 64);
    const float hpx = __shfl(ct.x, lp, 64);
    const float hpy = __shfl(ct.y, lp, 64);
    const float A2[4] = {a2.x, a2.y, a2.z, a2.w};
    const float A1[4] = {a1.x, a1.y, a1.z, a1.w};
    const float CT[4] = {ct.x, ct.y, ct.z, ct.w};
    const float B1[4] = {b1.x, b1.y, b1.z, b1.w};
    const float B2[4] = {b2.x, b2.y, b2.z, b2.w};
    const float RV[4] = {rv.x, rv.y, rv.z, rv.w};
    const float cc[8] = {hmx, hmy, ct.x, ct.y, ct.z, ct.w, hpx, hpy};
    const bool rowok = (gy >= 2) && (gy < HH - 2);
    float o[4];
#pragma unroll
    for (int k = 0; k < 4; ++k) {
        float v = RV[k];
        v = fmaf(cf.sH2, A2[k] + B2[k], v);
        v = fmaf(cf.sH1, A1[k] + B1[k], v);
        v = fmaf(cf.sW2, cc[k] + cc[k + 4], v);
        v = fmaf(cf.sW1, cc[k + 1] + cc[k + 3], v);
        if (EDGE) {
            const int gx = gx0 + k;
            const bool ok = rowok && (gx >= 2) && (gx < WW - 2);
            v = ok ? v : CT[k];
        }
        o[k] = v;
    }
    return make_float4(o[0], o[1], o[2], o[3]);
}

template <bool EDGE>
__device__ __forceinline__ void sweeps(
    float* xb, float* fz, float4 (&f)[8], float4 (&rv)[8], const Coef cf,
    const int oct, const int c, const int lm, const int lp,
    const int gyb, const int gx0, float* ob, const int x0, const int y0)
{
    // y-halo source/dest bases (compile-time-selected per sweep parity;
    // frz fallback for the outermost octets -> no control divergence)
    const float* pmu0 = (oct > 0) ? xb + ((oct - 1) * 4 + 2) * TWX + c : fz + 0 * TWX + c;
    const float* pmu1 = (oct > 0) ? pmu0 + XB : pmu0;
    const float* ppd0 = (oct < NOCT - 1) ? xb + ((oct + 1) * 4 + 0) * TWX + c : fz + 2 * TWX + c;
    const float* ppd1 = (oct < NOCT - 1) ? ppd0 + XB : ppd0;
    float* wr0 = xb + (oct * 4) * TWX + c;        // write base, buffer 0
    float* wr1 = wr0 + XB;                        // write base, buffer 1

#pragma unroll
    for (int it = 0; it < NITER; ++it) {
        const float* pmu = (it & 1) ? pmu1 : pmu0;   // read buffer it&1
        const float* ppd = (it & 1) ? ppd1 : ppd0;
        float* wr = (it & 1) ? wr0 : wr1;            // write buffer (it+1)&1

        const float4 fm2 = ld4(pmu);          // tile rows trow0-2, trow0-1
        const float4 fm1 = ld4(pmu + TWX);
        float4 o0 = row_update<EDGE>(fm2, fm1, f[0], f[1], f[2], rv[0], cf, lm, lp, gyb + 0, gx0);
        float4 o1 = row_update<EDGE>(fm1, f[0], f[1], f[2], f[3], rv[1], cf, lm, lp, gyb + 1, gx0);
        float4 o2 = row_update<EDGE>(f[0], f[1], f[2], f[3], f[4], rv[2], cf, lm, lp, gyb + 2, gx0);
        f[0] = o0;   // f[0] dead after o2 (rolling window caps o-liveness)
        float4 o3 = row_update<EDGE>(f[1], f[2], f[3], f[4], f[5], rv[3], cf, lm, lp, gyb + 3, gx0);
        f[1] = o1;
        float4 o4 = row_update<EDGE>(f[2], f[3], f[4], f[5], f[6], rv[4], cf, lm, lp, gyb + 4, gx0);
        f[2] = o2;
        float4 o5 = row_update<EDGE>(f[3], f[4], f[5], f[6], f[7], rv[5], cf, lm, lp, gyb + 5, gx0);
        f[3] = o3;
        const float4 fp0 = ld4(ppd);          // tile rows trow0+8, trow0+9
        const float4 fp1 = ld4(ppd + TWX);
        float4 o6 = row_update<EDGE>(f[4], f[5], f[6], f[7], fp0, rv[6], cf, lm, lp, gyb + 6, gx0);
        f[4] = o4;
        float4 o7 = row_update<EDGE>(f[5], f[6], f[7], fp0, fp1, rv[7], cf, lm, lp, gyb + 7, gx0);
        f[5] = o5;

        if (it < NITER - 1) {
            st4(wr + 0 * TWX, o0);   // publish new boundary rows {0,1,6,7}
            st4(wr + 1 * TWX, o1);
            st4(wr + 2 * TWX, o6);
            st4(wr + 3 * TWX, o7);
            f[6] = o6; f[7] = o7;
            __syncthreads();         // one barrier per sweep (ping-pong)
        } else {
            // final sweep: store center rows straight from registers
            const int gxl = x0 + c - HALO;
            const bool colok = (c >= HALO) && (c < HALO + TX) && (gxl <= WW - 4);
            if (colok) {
                const int trow0 = gyb - (y0 - HALO);
                const float4 oo[8] = {o0, o1, o2, o3, o4, o5, o6, o7};
#pragma unroll
                for (int j = 0; j < 8; ++j) {
                    const int tr = trow0 + j;
                    const int gy = y0 + tr - HALO;
                    if (tr >= HALO && tr < HALO + TY && gy < HH)
                        st4(ob + (size_t)gy * WW + gxl, oo[j]);
                }
            }
        }
    }
}

__global__ __launch_bounds__(NTHREADS, 4) void jacobi_fused(
    const float* __restrict__ g0, const float* __restrict__ rhs,
    const float* __restrict__ dx, float* __restrict__ out)
{
    __shared__ __align__(16) float xch[2][NOCT][4][TWX];   // 32 KiB ping-pong
    __shared__ __align__(16) float frz[4][TWX];            // 2 KiB frozen rows

    const int tid = (int)threadIdx.x;

    // XCD-chunked bijective swizzle: consecutive logical tiles share an XCD L2
    const int h = (int)blockIdx.x + GX * ((int)blockIdx.y + GY * (int)blockIdx.z);
    const int l = (h & (NXCD - 1)) * CHUNK + (h >> 3);
    const int tx = l % GX;
    const int t2 = l / GX;
    const int ty = t2 % GY;
    const int b  = t2 / GY;
    const int x0 = tx * TX, y0 = ty * TY;

    const float* gb = g0 + (size_t)b * HH * WW;
    const float* rb = rhs + (size_t)b * HH * WW;
    float* ob = out + (size_t)b * HH * WW;

    // per-batch coefficients (d_inv and the -cr sign folded in)
    const float t0 = 1.0f / dx[2 * b + 0], t1 = 1.0f / dx[2 * b + 1];
    const float p0 = t0 * t0, p1 = t1 * t1;
    const float d_inv = 1.0f / (-2.5f * (p0 + p1));
    Coef cf;
    cf.sH1 = -d_inv * (4.0f / 3.0f) * p0;
    cf.sH2 = -d_inv * (-1.0f / 12.0f) * p0;
    cf.sW1 = -d_inv * (4.0f / 3.0f) * p1;
    cf.sW2 = -d_inv * (-1.0f / 12.0f) * p1;

    // work item: octet oct (8 rows, tile rows 2+8*oct .. 9+8*oct) x 4 cols
    const int oct = tid >> 5;          // 0..7
    const int cg  = tid & 31;          // col group 0..31
    const int c   = 4 * cg;            // tile col 0..124
    const int lane = tid & 63;
    const int lm = (lane + 63) & 63;   // left neighbor lane (wrap: cone-safe)
    const int lp = (lane + 1) & 63;
    const int gx0 = x0 - HALO + c;
    const int trow0 = 2 + 8 * oct;
    const int gyb = y0 - HALO + trow0;

    // load octet state + scaled rhs into registers (clamp-replicate at edges)
    float4 f[8], rvv[8];
#pragma unroll
    for (int j = 0; j < 8; ++j) {
        f[j] = ld4g(gb, gyb + j, gx0);
        const float4 v = ld4g(rb, gyb + j, gx0);
        rvv[j] = make_float4(d_inv * v.x, d_inv * v.y, d_inv * v.z, d_inv * v.w);
    }

    // seed exchange buffer 0 with initial boundary rows + frozen outer rows
    st4(&xch[0][oct][0][c], f[0]);
    st4(&xch[0][oct][1][c], f[1]);
    st4(&xch[0][oct][2][c], f[6]);
    st4(&xch[0][oct][3][c], f[7]);
    if (oct == 0) {
        st4(&frz[0][c], ld4g(gb, y0 - HALO + 0, gx0));
        st4(&frz[1][c], ld4g(gb, y0 - HALO + 1, gx0));
    } else if (oct == NOCT - 1) {
        st4(&frz[2][c], ld4g(gb, y0 - HALO + 66, gx0));
        st4(&frz[3][c], ld4g(gb, y0 - HALO + 67, gx0));
    }
    __syncthreads();

    const bool interior = (x0 - HALO >= 2) && (x0 + TX + HALO <= WW - 2) &&
                          (y0 - HALO >= 2) && (y0 + TY + HALO <= HH - 2);
    if (interior)
        sweeps<false>(&xch[0][0][0][0], &frz[0][0], f, rvv, cf, oct, c, lm, lp, gyb, gx0, ob, x0, y0);
    else
        sweeps<true >(&xch[0][0][0][0], &frz[0][0], f, rvv, cf, oct, c, lm, lp, gyb, gx0, ob, x0, y0);
}

extern "C" void kernel_launch(void* const* d_in, const int* in_sizes, int n_in,
                              void* d_out, int out_size, void* d_ws, size_t ws_size,
                              hipStream_t stream) {
    const float* g0  = (const float*)d_in[0];
    const float* rhs = (const float*)d_in[1];
    const float* dx  = (const float*)d_in[2];
    float* out = (float*)d_out;

    dim3 grid(GX, GY, NB), block(NTHREADS);
    jacobi_fused<<<grid, block, 0, stream>>>(g0, rhs, dx, out);
}

// Round 5
// 216.176 us; speedup vs baseline: 1.8166x; 1.8166x over previous
//
#include <hip/hip_runtime.h>

// Fused 5-iteration Jacobi, cross-stencil, B=16, H=W=1024 fp32.
// R9 = R8's h=8 decomposition with the VGPR cap fixed.
// Empirical hipcc rule from R6/R7/R8 counters: __launch_bounds__ second arg
// alone sets the per-wave VGPR cap = 2048/(8*arg) (R6 arg8->32, R7/R8 arg4->64,
// independent of block size). R8's live set (f[8]+rv[8]+temps ~= 110) spilled
// at cap 64 -> FETCH 300MB / WRITE 444MB of scratch traffic, 305us. arg=2
// raises the cap to 128; occupancy is then LDS-bound at 4 blocks/CU
// (34 KiB * 4 = 136 <= 160) = 16 waves/CU = exactly the 2048-VGPR pool.
// Structure (unchanged from R8):
//  - Each thread owns an 8-row x 4-col octet in VGPRs; only boundary rows
//    {0,1,6,7} are exchanged via a ping-pong LDS buffer (rows 2-5 never
//    touch LDS): 0.25 b128/point vs R7's 0.5, half the threads of R7.
//  - Tile 128x68, compute rows 2..65, output 104x44, grid 10x24x16 = 3840
//    blocks = exactly 15 blocks/CU.
//  - x-halos via __shfl from neighbor lanes; y-halos: 2 b128 up + 2 down.
//  - Rolling register window caps o-temp liveness; final sweep stores
//    straight from registers; XCD-chunked bijective swizzle (3840 = 8*480).
// Cone safety: stored rows 12..55 <- computed rows 2..65; stored cols
// 12..115 <- cols 2..125; shuffle-wrap garbage cols {0,1,126,127} and frozen
// rows {0,1,66,67} stay outside the 5-sweep dependency cone.

#define HH 1024
#define WW 1024
#define NB 16
#define GX 10
#define GY 24
#define TX 104
#define TY 44
#define HALO 12
#define TWX 128            // LDS row stride (floats), %32 banks == 0
#define NOCT 8
#define NTHREADS 256
#define NITER 5
#define NBLK (GX * GY * NB)   // 3840
#define NXCD 8
#define CHUNK (NBLK / NXCD)   // 480 (exact -> bijective)
#define XB (NOCT * 4 * TWX)   // floats per exchange buffer (4096)
#define FZOFF (2 * XB)        // frozen rows live after the two ping-pong buffers

struct Coef { float sH1, sH2, sW1, sW2; };

__device__ __forceinline__ float4 ld4(const float* p) { return *(const float4*)p; }
__device__ __forceinline__ void st4(float* p, float4 v) { *(float4*)p = v; }

// clamp-replicate float4 load (global tile/rhs loads; one-time)
__device__ __forceinline__ float4 ld4g(const float* img, int gy, int gxl) {
    gy = gy < 0 ? 0 : (gy > HH - 1 ? HH - 1 : gy);
    const float* row = img + (size_t)gy * WW;
    if (gxl >= 0 && gxl <= WW - 4) return ld4(row + gxl);
    int xa = gxl + 0; xa = xa < 0 ? 0 : (xa > WW - 1 ? WW - 1 : xa);
    int xb = gxl + 1; xb = xb < 0 ? 0 : (xb > WW - 1 ? WW - 1 : xb);
    int xc = gxl + 2; xc = xc < 0 ? 0 : (xc > WW - 1 ? WW - 1 : xc);
    int xd = gxl + 3; xd = xd < 0 ? 0 : (xd > WW - 1 ? WW - 1 : xd);
    return make_float4(row[xa], row[xb], row[xc], row[xd]);
}

template <bool EDGE>
__device__ __forceinline__ float4 row_update(
    const float4 a2, const float4 a1, const float4 ct, const float4 b1, const float4 b2,
    const float4 rv, const Coef cf, const int lm, const int lp,
    const int gy, const int gx0)
{
    // x-halo from neighbor lanes' registers (ds_bpermute crossbar, conflict-free)
    const float hmx = __shfl(ct.z, lm, 64);
    const float hmy = __shfl(ct.w, lm, 64);
    const float hpx = __shfl(ct.x, lp, 64);
    const float hpy = __shfl(ct.y, lp, 64);
    const float A2[4] = {a2.x, a2.y, a2.z, a2.w};
    const float A1[4] = {a1.x, a1.y, a1.z, a1.w};
    const float CT[4] = {ct.x, ct.y, ct.z, ct.w};
    const float B1[4] = {b1.x, b1.y, b1.z, b1.w};
    const float B2[4] = {b2.x, b2.y, b2.z, b2.w};
    const float RV[4] = {rv.x, rv.y, rv.z, rv.w};
    const float cc[8] = {hmx, hmy, ct.x, ct.y, ct.z, ct.w, hpx, hpy};
    const bool rowok = (gy >= 2) && (gy < HH - 2);
    float o[4];
#pragma unroll
    for (int k = 0; k < 4; ++k) {
        float v = RV[k];
        v = fmaf(cf.sH2, A2[k] + B2[k], v);
        v = fmaf(cf.sH1, A1[k] + B1[k], v);
        v = fmaf(cf.sW2, cc[k] + cc[k + 4], v);
        v = fmaf(cf.sW1, cc[k + 1] + cc[k + 3], v);
        if (EDGE) {
            const int gx = gx0 + k;
            const bool ok = rowok && (gx >= 2) && (gx < WW - 2);
            v = ok ? v : CT[k];
        }
        o[k] = v;
    }
    return make_float4(o[0], o[1], o[2], o[3]);
}

template <bool EDGE>
__device__ __forceinline__ void sweeps(
    float* lds, float4 (&f)[8], float4 (&rv)[8], const Coef cf,
    const int oct, const int c, const int lm, const int lp,
    const int gyb, const int gx0, float* ob, const int x0, const int y0)
{
    // y-halo read bases (buffer 0; buffer 1 = +XB compile-time offset).
    // Outermost octets read frozen rows (same both parities).
    const float* pmu = (oct > 0) ? lds + ((oct - 1) * 4 + 2) * TWX + c
                                 : lds + FZOFF + 0 * TWX + c;
    const float* ppd = (oct < NOCT - 1) ? lds + ((oct + 1) * 4 + 0) * TWX + c
                                        : lds + FZOFF + 2 * TWX + c;
    const int mo = (oct > 0) ? XB : 0;          // parity offset (0 for frz)
    const int po = (oct < NOCT - 1) ? XB : 0;
    float* wr = lds + (oct * 4) * TWX + c;      // write base, buffer 0

#pragma unroll
    for (int it = 0; it < NITER; ++it) {
        const int ro = (it & 1) ? mo : 0;       // read parity offset (up)
        const int rp = (it & 1) ? po : 0;       //                    (down)
        const int wo = (it & 1) ? 0 : XB;       // write parity offset

        const float4 fm2 = ld4(pmu + ro);
        const float4 fm1 = ld4(pmu + ro + TWX);
        float4 o0 = row_update<EDGE>(fm2, fm1, f[0], f[1], f[2], rv[0], cf, lm, lp, gyb + 0, gx0);
        float4 o1 = row_update<EDGE>(fm1, f[0], f[1], f[2], f[3], rv[1], cf, lm, lp, gyb + 1, gx0);
        float4 o2 = row_update<EDGE>(f[0], f[1], f[2], f[3], f[4], rv[2], cf, lm, lp, gyb + 2, gx0);
        f[0] = o0;   // rolling window: f[j] replaced right after last use
        float4 o3 = row_update<EDGE>(f[1], f[2], f[3], f[4], f[5], rv[3], cf, lm, lp, gyb + 3, gx0);
        f[1] = o1;
        float4 o4 = row_update<EDGE>(f[2], f[3], f[4], f[5], f[6], rv[4], cf, lm, lp, gyb + 4, gx0);
        f[2] = o2;
        float4 o5 = row_update<EDGE>(f[3], f[4], f[5], f[6], f[7], rv[5], cf, lm, lp, gyb + 5, gx0);
        f[3] = o3;
        const float4 fp0 = ld4(ppd + rp);
        const float4 fp1 = ld4(ppd + rp + TWX);
        float4 o6 = row_update<EDGE>(f[4], f[5], f[6], f[7], fp0, rv[6], cf, lm, lp, gyb + 6, gx0);
        f[4] = o4;
        float4 o7 = row_update<EDGE>(f[5], f[6], f[7], fp0, fp1, rv[7], cf, lm, lp, gyb + 7, gx0);
        f[5] = o5;

        if (it < NITER - 1) {
            st4(wr + wo + 0 * TWX, o0);   // publish boundary rows {0,1,6,7}
            st4(wr + wo + 1 * TWX, o1);
            st4(wr + wo + 2 * TWX, o6);
            st4(wr + wo + 3 * TWX, o7);
            f[6] = o6; f[7] = o7;
            __syncthreads();              // one barrier per sweep (ping-pong)
        } else {
            // final sweep: store center rows straight from registers
            const int gxl = x0 + c - HALO;
            if ((c >= HALO) && (c < HALO + TX) && (gxl <= WW - 4)) {
                const int trow0 = gyb - (y0 - HALO);
                float* obase = ob + (size_t)(y0 + trow0 - HALO) * WW + gxl;
                const int gylim = HH - (y0 + trow0 - HALO);  // rows storable
#define ST_ROW(J, OJ) \
                if (trow0 + (J) >= HALO && trow0 + (J) < HALO + TY && (J) < gylim) \
                    st4(obase + (size_t)(J) * WW, OJ);
                ST_ROW(0, o0) ST_ROW(1, o1) ST_ROW(2, o2) ST_ROW(3, o3)
                ST_ROW(4, o4) ST_ROW(5, o5) ST_ROW(6, o6) ST_ROW(7, o7)
#undef ST_ROW
            }
        }
    }
}

__global__ __launch_bounds__(NTHREADS, 2) void jacobi_fused(
    const float* __restrict__ g0, const float* __restrict__ rhs,
    const float* __restrict__ dx, float* __restrict__ out)
{
    // [2 ping-pong exchange buffers | 4 frozen rows] = 32 KiB + 2 KiB
    __shared__ __align__(16) float lds[2 * XB + 4 * TWX];

    const int tid = (int)threadIdx.x;

    // XCD-chunked bijective swizzle: consecutive logical tiles share an XCD L2
    const int h = (int)blockIdx.x + GX * ((int)blockIdx.y + GY * (int)blockIdx.z);
    const int l = (h & (NXCD - 1)) * CHUNK + (h >> 3);
    const int tx = l % GX;
    const int t2 = l / GX;
    const int ty = t2 % GY;
    const int b  = t2 / GY;
    const int x0 = tx * TX, y0 = ty * TY;

    const float* gb = g0 + (size_t)b * HH * WW;
    const float* rb = rhs + (size_t)b * HH * WW;
    float* ob = out + (size_t)b * HH * WW;

    // per-batch coefficients (d_inv and the -cr sign folded in)
    const float t0 = 1.0f / dx[2 * b + 0], t1 = 1.0f / dx[2 * b + 1];
    const float p0 = t0 * t0, p1 = t1 * t1;
    const float d_inv = 1.0f / (-2.5f * (p0 + p1));
    Coef cf;
    cf.sH1 = -d_inv * (4.0f / 3.0f) * p0;
    cf.sH2 = -d_inv * (-1.0f / 12.0f) * p0;
    cf.sW1 = -d_inv * (4.0f / 3.0f) * p1;
    cf.sW2 = -d_inv * (-1.0f / 12.0f) * p1;

    // work item: octet oct (tile rows 2+8*oct .. 9+8*oct) x 4 cols
    const int oct = tid >> 5;          // 0..7
    const int cg  = tid & 31;          // col group 0..31
    const int c   = 4 * cg;            // tile col 0..124
    const int lane = tid & 63;
    const int lm = (lane + 63) & 63;   // left neighbor lane (wrap: cone-safe)
    const int lp = (lane + 1) & 63;
    const int gx0 = x0 - HALO + c;
    const int trow0 = 2 + 8 * oct;
    const int gyb = y0 - HALO + trow0;

    // load octet state + scaled rhs into registers (clamp-replicate at edges)
    float4 f[8], rvv[8];
#pragma unroll
    for (int j = 0; j < 8; ++j) {
        f[j] = ld4g(gb, gyb + j, gx0);
        const float4 v = ld4g(rb, gyb + j, gx0);
        rvv[j] = make_float4(d_inv * v.x, d_inv * v.y, d_inv * v.z, d_inv * v.w);
    }

    // seed exchange buffer 0 with initial boundary rows + frozen outer rows
    st4(&lds[(oct * 4 + 0) * TWX + c], f[0]);
    st4(&lds[(oct * 4 + 1) * TWX + c], f[1]);
    st4(&lds[(oct * 4 + 2) * TWX + c], f[6]);
    st4(&lds[(oct * 4 + 3) * TWX + c], f[7]);
    if (oct == 0) {
        st4(&lds[FZOFF + 0 * TWX + c], ld4g(gb, y0 - HALO + 0, gx0));
        st4(&lds[FZOFF + 1 * TWX + c], ld4g(gb, y0 - HALO + 1, gx0));
    } else if (oct == NOCT - 1) {
        st4(&lds[FZOFF + 2 * TWX + c], ld4g(gb, y0 - HALO + 66, gx0));
        st4(&lds[FZOFF + 3 * TWX + c], ld4g(gb, y0 - HALO + 67, gx0));
    }
    __syncthreads();

    const bool interior = (x0 - HALO >= 2) && (x0 + TX + HALO <= WW - 2) &&
                          (y0 - HALO >= 2) && (y0 + TY + HALO <= HH - 2);
    if (interior)
        sweeps<false>(lds, f, rvv, cf, oct, c, lm, lp, gyb, gx0, ob, x0, y0);
    else
        sweeps<true >(lds, f, rvv, cf, oct, c, lm, lp, gyb, gx0, ob, x0, y0);
}

extern "C" void kernel_launch(void* const* d_in, const int* in_sizes, int n_in,
                              void* d_out, int out_size, void* d_ws, size_t ws_size,
                              hipStream_t stream) {
    const float* g0  = (const float*)d_in[0];
    const float* rhs = (const float*)d_in[1];
    const float* dx  = (const float*)d_in[2];
    float* out = (float*)d_out;

    dim3 grid(GX, GY, NB), block(NTHREADS);
    jacobi_fused<<<grid, block, 0, stream>>>(g0, rhs, dx, out);
}

// Round 6
// 212.743 us; speedup vs baseline: 1.8459x; 1.0161x over previous
//
#include <hip/hip_runtime.h>

// Fused 5-iteration Jacobi, cross-stencil, B=16, H=W=1024 fp32.
// R10 = R9 with x-halos moved from ds_bpermute (__shfl) to DPP.
// R9 accounting: DS pipe is per-CU; 60 waves/CU x 5 sweeps x (32 bpermute +
// 8 b128) ~= 44us of DS busy, ~75% of it the x-halo shuffles, plus 8 serial
// lgkmcnt stalls per sweep waiting on shuffle batches. DPP wave_shr:1
// (lane i <- i-1, ctrl 0x138) / wave_shl:1 (lane i <- i+1, ctrl 0x130) do the
// same +-1-lane move as a VALU operand modifier: no DS usage, no lgkm wait.
// Cone safety of the seams is unchanged from R9's wrap-shuffle: lane 0/63
// bound_ctrl-zeros and the lane-31/32 octet seam only corrupt halo cols
// {-2,-1,128,129} -> output cols {0,1,126,127}, all outside the 5-sweep
// dependency cone of the stored center (cols [12,116) <- cols [2,126)).
// All 256 threads are convergent at the DPP sites (EXEC full). Everything
// else identical to R9:
//  - h=8 octet per thread in VGPRs; boundary rows {0,1,6,7} exchanged via
//    ping-pong LDS (0.25 b128/point); tile 128x68, output 104x44,
//    grid 10x24x16 = 3840 = exactly 15 blocks/CU.
//  - __launch_bounds__(256,2) -> 128-VGPR cap (R9 measured 120, no spill;
//    FETCH/WRITE at the 65.7/65.5 MB minimum -- spill tripwire).
//  - Rolling register window; final sweep stores from registers;
//    XCD-chunked bijective swizzle (3840 = 8*480).

#define HH 1024
#define WW 1024
#define NB 16
#define GX 10
#define GY 24
#define TX 104
#define TY 44
#define HALO 12
#define TWX 128            // LDS row stride (floats), %32 banks == 0
#define NOCT 8
#define NTHREADS 256
#define NITER 5
#define NBLK (GX * GY * NB)   // 3840
#define NXCD 8
#define CHUNK (NBLK / NXCD)   // 480 (exact -> bijective)
#define XB (NOCT * 4 * TWX)   // floats per exchange buffer (4096)
#define FZOFF (2 * XB)        // frozen rows after the two ping-pong buffers

struct Coef { float sH1, sH2, sW1, sW2; };

__device__ __forceinline__ float4 ld4(const float* p) { return *(const float4*)p; }
__device__ __forceinline__ void st4(float* p, float4 v) { *(float4*)p = v; }

// DPP lane moves (VALU pipe, no DS, no lgkmcnt). bound_ctrl=1 -> OOB lanes 0.
__device__ __forceinline__ float dpp_shr1(float x) {   // lane i <- lane i-1
    return __int_as_float(__builtin_amdgcn_update_dpp(
        0, __float_as_int(x), 0x138 /*wave_shr:1*/, 0xf, 0xf, true));
}
__device__ __forceinline__ float dpp_shl1(float x) {   // lane i <- lane i+1
    return __int_as_float(__builtin_amdgcn_update_dpp(
        0, __float_as_int(x), 0x130 /*wave_shl:1*/, 0xf, 0xf, true));
}

// clamp-replicate float4 load (global tile/rhs loads; one-time)
__device__ __forceinline__ float4 ld4g(const float* img, int gy, int gxl) {
    gy = gy < 0 ? 0 : (gy > HH - 1 ? HH - 1 : gy);
    const float* row = img + (size_t)gy * WW;
    if (gxl >= 0 && gxl <= WW - 4) return ld4(row + gxl);
    int xa = gxl + 0; xa = xa < 0 ? 0 : (xa > WW - 1 ? WW - 1 : xa);
    int xb = gxl + 1; xb = xb < 0 ? 0 : (xb > WW - 1 ? WW - 1 : xb);
    int xc = gxl + 2; xc = xc < 0 ? 0 : (xc > WW - 1 ? WW - 1 : xc);
    int xd = gxl + 3; xd = xd < 0 ? 0 : (xd > WW - 1 ? WW - 1 : xd);
    return make_float4(row[xa], row[xb], row[xc], row[xd]);
}

template <bool EDGE>
__device__ __forceinline__ float4 row_update(
    const float4 a2, const float4 a1, const float4 ct, const float4 b1, const float4 b2,
    const float4 rv, const Coef cf, const int gy, const int gx0)
{
    // x-halo from neighbor lanes via DPP (seam/boundary garbage is cone-safe)
    const float hmx = dpp_shr1(ct.z);
    const float hmy = dpp_shr1(ct.w);
    const float hpx = dpp_shl1(ct.x);
    const float hpy = dpp_shl1(ct.y);
    const float A2[4] = {a2.x, a2.y, a2.z, a2.w};
    const float A1[4] = {a1.x, a1.y, a1.z, a1.w};
    const float CT[4] = {ct.x, ct.y, ct.z, ct.w};
    const float B1[4] = {b1.x, b1.y, b1.z, b1.w};
    const float B2[4] = {b2.x, b2.y, b2.z, b2.w};
    const float RV[4] = {rv.x, rv.y, rv.z, rv.w};
    const float cc[8] = {hmx, hmy, ct.x, ct.y, ct.z, ct.w, hpx, hpy};
    const bool rowok = (gy >= 2) && (gy < HH - 2);
    float o[4];
#pragma unroll
    for (int k = 0; k < 4; ++k) {
        float v = RV[k];
        v = fmaf(cf.sH2, A2[k] + B2[k], v);
        v = fmaf(cf.sH1, A1[k] + B1[k], v);
        v = fmaf(cf.sW2, cc[k] + cc[k + 4], v);
        v = fmaf(cf.sW1, cc[k + 1] + cc[k + 3], v);
        if (EDGE) {
            const int gx = gx0 + k;
            const bool ok = rowok && (gx >= 2) && (gx < WW - 2);
            v = ok ? v : CT[k];
        }
        o[k] = v;
    }
    return make_float4(o[0], o[1], o[2], o[3]);
}

template <bool EDGE>
__device__ __forceinline__ void sweeps(
    float* lds, float4 (&f)[8], float4 (&rv)[8], const Coef cf,
    const int oct, const int c, const int gyb, const int gx0,
    float* ob, const int x0, const int y0)
{
    // y-halo read bases (buffer 0; buffer 1 = +XB). Outermost octets read
    // frozen rows (same both parities).
    const float* pmu = (oct > 0) ? lds + ((oct - 1) * 4 + 2) * TWX + c
                                 : lds + FZOFF + 0 * TWX + c;
    const float* ppd = (oct < NOCT - 1) ? lds + ((oct + 1) * 4 + 0) * TWX + c
                                        : lds + FZOFF + 2 * TWX + c;
    const int mo = (oct > 0) ? XB : 0;          // parity offset (0 for frz)
    const int po = (oct < NOCT - 1) ? XB : 0;
    float* wr = lds + (oct * 4) * TWX + c;      // write base, buffer 0

#pragma unroll
    for (int it = 0; it < NITER; ++it) {
        const int ro = (it & 1) ? mo : 0;       // read parity offset (up)
        const int rp = (it & 1) ? po : 0;       //                    (down)
        const int wo = (it & 1) ? 0 : XB;       // write parity offset

        const float4 fm2 = ld4(pmu + ro);
        const float4 fm1 = ld4(pmu + ro + TWX);
        float4 o0 = row_update<EDGE>(fm2, fm1, f[0], f[1], f[2], rv[0], cf, gyb + 0, gx0);
        float4 o1 = row_update<EDGE>(fm1, f[0], f[1], f[2], f[3], rv[1], cf, gyb + 1, gx0);
        float4 o2 = row_update<EDGE>(f[0], f[1], f[2], f[3], f[4], rv[2], cf, gyb + 2, gx0);
        f[0] = o0;   // rolling window: f[j] replaced right after last use
        float4 o3 = row_update<EDGE>(f[1], f[2], f[3], f[4], f[5], rv[3], cf, gyb + 3, gx0);
        f[1] = o1;
        float4 o4 = row_update<EDGE>(f[2], f[3], f[4], f[5], f[6], rv[4], cf, gyb + 4, gx0);
        f[2] = o2;
        float4 o5 = row_update<EDGE>(f[3], f[4], f[5], f[6], f[7], rv[5], cf, gyb + 5, gx0);
        f[3] = o3;
        const float4 fp0 = ld4(ppd + rp);
        const float4 fp1 = ld4(ppd + rp + TWX);
        float4 o6 = row_update<EDGE>(f[4], f[5], f[6], f[7], fp0, rv[6], cf, gyb + 6, gx0);
        f[4] = o4;
        float4 o7 = row_update<EDGE>(f[5], f[6], f[7], fp0, fp1, rv[7], cf, gyb + 7, gx0);
        f[5] = o5;

        if (it < NITER - 1) {
            st4(wr + wo + 0 * TWX, o0);   // publish boundary rows {0,1,6,7}
            st4(wr + wo + 1 * TWX, o1);
            st4(wr + wo + 2 * TWX, o6);
            st4(wr + wo + 3 * TWX, o7);
            f[6] = o6; f[7] = o7;
            __syncthreads();              // one barrier per sweep (ping-pong)
        } else {
            // final sweep: store center rows straight from registers
            const int gxl = x0 + c - HALO;
            if ((c >= HALO) && (c < HALO + TX) && (gxl <= WW - 4)) {
                const int trow0 = gyb - (y0 - HALO);
                float* obase = ob + (size_t)(y0 + trow0 - HALO) * WW + gxl;
                const int gylim = HH - (y0 + trow0 - HALO);  // rows storable
#define ST_ROW(J, OJ) \
                if (trow0 + (J) >= HALO && trow0 + (J) < HALO + TY && (J) < gylim) \
                    st4(obase + (size_t)(J) * WW, OJ);
                ST_ROW(0, o0) ST_ROW(1, o1) ST_ROW(2, o2) ST_ROW(3, o3)
                ST_ROW(4, o4) ST_ROW(5, o5) ST_ROW(6, o6) ST_ROW(7, o7)
#undef ST_ROW
            }
        }
    }
}

__global__ __launch_bounds__(NTHREADS, 2) void jacobi_fused(
    const float* __restrict__ g0, const float* __restrict__ rhs,
    const float* __restrict__ dx, float* __restrict__ out)
{
    // [2 ping-pong exchange buffers | 4 frozen rows] = 32 KiB + 2 KiB
    __shared__ __align__(16) float lds[2 * XB + 4 * TWX];

    const int tid = (int)threadIdx.x;

    // XCD-chunked bijective swizzle: consecutive logical tiles share an XCD L2
    const int h = (int)blockIdx.x + GX * ((int)blockIdx.y + GY * (int)blockIdx.z);
    const int l = (h & (NXCD - 1)) * CHUNK + (h >> 3);
    const int tx = l % GX;
    const int t2 = l / GX;
    const int ty = t2 % GY;
    const int b  = t2 / GY;
    const int x0 = tx * TX, y0 = ty * TY;

    const float* gb = g0 + (size_t)b * HH * WW;
    const float* rb = rhs + (size_t)b * HH * WW;
    float* ob = out + (size_t)b * HH * WW;

    // per-batch coefficients (d_inv and the -cr sign folded in)
    const float t0 = 1.0f / dx[2 * b + 0], t1 = 1.0f / dx[2 * b + 1];
    const float p0 = t0 * t0, p1 = t1 * t1;
    const float d_inv = 1.0f / (-2.5f * (p0 + p1));
    Coef cf;
    cf.sH1 = -d_inv * (4.0f / 3.0f) * p0;
    cf.sH2 = -d_inv * (-1.0f / 12.0f) * p0;
    cf.sW1 = -d_inv * (4.0f / 3.0f) * p1;
    cf.sW2 = -d_inv * (-1.0f / 12.0f) * p1;

    // work item: octet oct (tile rows 2+8*oct .. 9+8*oct) x 4 cols
    const int oct = tid >> 5;          // 0..7
    const int cg  = tid & 31;          // col group 0..31
    const int c   = 4 * cg;            // tile col 0..124
    const int gx0 = x0 - HALO + c;
    const int trow0 = 2 + 8 * oct;
    const int gyb = y0 - HALO + trow0;

    // load octet state + scaled rhs into registers (clamp-replicate at edges)
    float4 f[8], rvv[8];
#pragma unroll
    for (int j = 0; j < 8; ++j) {
        f[j] = ld4g(gb, gyb + j, gx0);
        const float4 v = ld4g(rb, gyb + j, gx0);
        rvv[j] = make_float4(d_inv * v.x, d_inv * v.y, d_inv * v.z, d_inv * v.w);
    }

    // seed exchange buffer 0 with initial boundary rows + frozen outer rows
    st4(&lds[(oct * 4 + 0) * TWX + c], f[0]);
    st4(&lds[(oct * 4 + 1) * TWX + c], f[1]);
    st4(&lds[(oct * 4 + 2) * TWX + c], f[6]);
    st4(&lds[(oct * 4 + 3) * TWX + c], f[7]);
    if (oct == 0) {
        st4(&lds[FZOFF + 0 * TWX + c], ld4g(gb, y0 - HALO + 0, gx0));
        st4(&lds[FZOFF + 1 * TWX + c], ld4g(gb, y0 - HALO + 1, gx0));
    } else if (oct == NOCT - 1) {
        st4(&lds[FZOFF + 2 * TWX + c], ld4g(gb, y0 - HALO + 66, gx0));
        st4(&lds[FZOFF + 3 * TWX + c], ld4g(gb, y0 - HALO + 67, gx0));
    }
    __syncthreads();

    const bool interior = (x0 - HALO >= 2) && (x0 + TX + HALO <= WW - 2) &&
                          (y0 - HALO >= 2) && (y0 + TY + HALO <= HH - 2);
    if (interior)
        sweeps<false>(lds, f, rvv, cf, oct, c, gyb, gx0, ob, x0, y0);
    else
        sweeps<true >(lds, f, rvv, cf, oct, c, gyb, gx0, ob, x0, y0);
}

extern "C" void kernel_launch(void* const* d_in, const int* in_sizes, int n_in,
                              void* d_out, int out_size, void* d_ws, size_t ws_size,
                              hipStream_t stream) {
    const float* g0  = (const float*)d_in[0];
    const float* rhs = (const float*)d_in[1];
    const float* dx  = (const float*)d_in[2];
    float* out = (float*)d_out;

    dim3 grid(GX, GY, NB), block(NTHREADS);
    jacobi_fused<<<grid, block, 0, stream>>>(g0, rhs, dx, out);
}

// Round 8
// 202.126 us; speedup vs baseline: 1.9429x; 1.0525x over previous
//
#include <hip/hip_runtime.h>

// Fused 5-iteration Jacobi, cross-stencil, B=16, H=W=1024 fp32.
// R11 (retry; previous round's failure was a container/infra error, kernel
// re-audited: clamped loads, guarded stores, LDS in-bounds, cone math ok).
// R11 = R10 + two TLP/work levers (structure otherwise identical):
//  1. Frozen halo rows live in REGISTERS of the outer octets (fz0/fz1),
//     not LDS: only octet 0 reads tile rows {0,1} and octet 7 rows {66,67}.
//     LDS drops 34816 -> 32768 B == exactly 5 blocks/CU (160 KiB), i.e.
//     20 waves/CU (+25% latency coverage) IF VGPR <= 102 (R10 measured 92,
//     +8 for fz ~= 100). R7/R10 showed DS/VALU pipes are NOT the limit --
//     wall/VALU ~3x is dependent-chain latency at 4 waves/SIMD.
//  2. Asymmetric halo: HALOY=10 (the true 5-sweep * radius-2 requirement).
//     Frozen rows go stale after sweep 1; wrongness grows 2 rows/sweep ->
//     after 5 sweeps tile rows 2..9 and 58..65 are polluted, rows [10,58)=48
//     valid. TY 44->48, grid 10x22x16 = 3520 blocks (-8.3% work; 3520=8*440
//     keeps the XCD swizzle bijective). x keeps HALOX=12 (float4 alignment
//     requires x-origin % 4 == 0); valid cols [10,118) strictly contain the
//     stored [12,116). At true domain edges the EDGE mask freezes global
//     rows/cols {0,1,1022,1023} every sweep, firewalling clamp-replicated
//     fake halo data from the stored region.
// Carried from R10/R9: h=8 octet per thread in VGPRs; boundary rows
// {0,1,6,7} exchanged via ping-pong LDS (0.25 b128/pt); x-halos via DPP
// wave_shr:1/wave_shl:1 (VALU pipe, no DS, no lgkm waits; seam garbage at
// cols {0,1,126,127} is outside the cone); rolling register window;
// __launch_bounds__(256,2) = 128-VGPR cap (spill tripwire: FETCH/WRITE
// must stay ~65 MB); final sweep stores from registers.

#define HH 1024
#define WW 1024
#define NB 16
#define GX 10
#define GY 22              // ceil(1024/48)
#define TX 104
#define TY 48
#define HALOX 12
#define HALOY 10
#define TWX 128            // LDS row stride (floats), %32 banks == 0
#define TWY 68             // tile height: 2 frozen + 64 computed + 2 frozen
#define NOCT 8
#define NTHREADS 256
#define NITER 5
#define NBLK (GX * GY * NB)   // 3520
#define NXCD 8
#define CHUNK (NBLK / NXCD)   // 440 (exact -> bijective)
#define XB (NOCT * 4 * TWX)   // floats per exchange buffer (4096)

struct Coef { float sH1, sH2, sW1, sW2; };

__device__ __forceinline__ float4 ld4(const float* p) { return *(const float4*)p; }
__device__ __forceinline__ void st4(float* p, float4 v) { *(float4*)p = v; }

// DPP lane moves (VALU pipe, no DS, no lgkmcnt). bound_ctrl=1 -> OOB lanes 0.
__device__ __forceinline__ float dpp_shr1(float x) {   // lane i <- lane i-1
    return __int_as_float(__builtin_amdgcn_update_dpp(
        0, __float_as_int(x), 0x138 /*wave_shr:1*/, 0xf, 0xf, true));
}
__device__ __forceinline__ float dpp_shl1(float x) {   // lane i <- lane i+1
    return __int_as_float(__builtin_amdgcn_update_dpp(
        0, __float_as_int(x), 0x130 /*wave_shl:1*/, 0xf, 0xf, true));
}

// clamp-replicate float4 load (global tile/rhs loads; one-time)
__device__ __forceinline__ float4 ld4g(const float* img, int gy, int gxl) {
    gy = gy < 0 ? 0 : (gy > HH - 1 ? HH - 1 : gy);
    const float* row = img + (size_t)gy * WW;
    if (gxl >= 0 && gxl <= WW - 4) return ld4(row + gxl);
    int xa = gxl + 0; xa = xa < 0 ? 0 : (xa > WW - 1 ? WW - 1 : xa);
    int xb = gxl + 1; xb = xb < 0 ? 0 : (xb > WW - 1 ? WW - 1 : xb);
    int xc = gxl + 2; xc = xc < 0 ? 0 : (xc > WW - 1 ? WW - 1 : xc);
    int xd = gxl + 3; xd = xd < 0 ? 0 : (xd > WW - 1 ? WW - 1 : xd);
    return make_float4(row[xa], row[xb], row[xc], row[xd]);
}

template <bool EDGE>
__device__ __forceinline__ float4 row_update(
    const float4 a2, const float4 a1, const float4 ct, const float4 b1, const float4 b2,
    const float4 rv, const Coef cf, const int gy, const int gx0)
{
    // x-halo from neighbor lanes via DPP (seam/boundary garbage is cone-safe)
    const float hmx = dpp_shr1(ct.z);
    const float hmy = dpp_shr1(ct.w);
    const float hpx = dpp_shl1(ct.x);
    const float hpy = dpp_shl1(ct.y);
    const float A2[4] = {a2.x, a2.y, a2.z, a2.w};
    const float A1[4] = {a1.x, a1.y, a1.z, a1.w};
    const float CT[4] = {ct.x, ct.y, ct.z, ct.w};
    const float B1[4] = {b1.x, b1.y, b1.z, b1.w};
    const float B2[4] = {b2.x, b2.y, b2.z, b2.w};
    const float RV[4] = {rv.x, rv.y, rv.z, rv.w};
    const float cc[8] = {hmx, hmy, ct.x, ct.y, ct.z, ct.w, hpx, hpy};
    const bool rowok = (gy >= 2) && (gy < HH - 2);
    float o[4];
#pragma unroll
    for (int k = 0; k < 4; ++k) {
        float v = RV[k];
        v = fmaf(cf.sH2, A2[k] + B2[k], v);
        v = fmaf(cf.sH1, A1[k] + B1[k], v);
        v = fmaf(cf.sW2, cc[k] + cc[k + 4], v);
        v = fmaf(cf.sW1, cc[k + 1] + cc[k + 3], v);
        if (EDGE) {
            const int gx = gx0 + k;
            const bool ok = rowok && (gx >= 2) && (gx < WW - 2);
            v = ok ? v : CT[k];
        }
        o[k] = v;
    }
    return make_float4(o[0], o[1], o[2], o[3]);
}

template <bool EDGE>
__device__ __forceinline__ void sweeps(
    float* lds, float4 (&f)[8], float4 (&rv)[8],
    const float4 fz0, const float4 fz1, const Coef cf,
    const int oct, const int c, const int gyb, const int gx0,
    float* ob, const int x0, const int y0)
{
    // y-halo read bases in exchange buffer 0 (buffer 1 = +XB); octet 0 / 7
    // use the fz registers instead (indices clamped so no OOB pointer math)
    const float* pmu = lds + ((oct > 0 ? oct - 1 : 0) * 4 + 2) * TWX + c;
    const float* ppd = lds + ((oct < NOCT - 1 ? oct + 1 : oct) * 4 + 0) * TWX + c;
    float* wr = lds + (oct * 4) * TWX + c;      // write base, buffer 0

#pragma unroll
    for (int it = 0; it < NITER; ++it) {
        const int ro = (it & 1) ? XB : 0;       // read parity offset
        const int wo = (it & 1) ? 0 : XB;       // write parity offset

        float4 fm2, fm1;
        if (oct > 0) { fm2 = ld4(pmu + ro); fm1 = ld4(pmu + ro + TWX); }
        else         { fm2 = fz0; fm1 = fz1; }   // frozen rows in registers
        float4 o0 = row_update<EDGE>(fm2, fm1, f[0], f[1], f[2], rv[0], cf, gyb + 0, gx0);
        float4 o1 = row_update<EDGE>(fm1, f[0], f[1], f[2], f[3], rv[1], cf, gyb + 1, gx0);
        float4 o2 = row_update<EDGE>(f[0], f[1], f[2], f[3], f[4], rv[2], cf, gyb + 2, gx0);
        f[0] = o0;   // rolling window: f[j] replaced right after last use
        float4 o3 = row_update<EDGE>(f[1], f[2], f[3], f[4], f[5], rv[3], cf, gyb + 3, gx0);
        f[1] = o1;
        float4 o4 = row_update<EDGE>(f[2], f[3], f[4], f[5], f[6], rv[4], cf, gyb + 4, gx0);
        f[2] = o2;
        float4 o5 = row_update<EDGE>(f[3], f[4], f[5], f[6], f[7], rv[5], cf, gyb + 5, gx0);
        f[3] = o3;
        float4 fp0, fp1;
        if (oct < NOCT - 1) { fp0 = ld4(ppd + ro); fp1 = ld4(ppd + ro + TWX); }
        else                { fp0 = fz0; fp1 = fz1; }
        float4 o6 = row_update<EDGE>(f[4], f[5], f[6], f[7], fp0, rv[6], cf, gyb + 6, gx0);
        f[4] = o4;
        float4 o7 = row_update<EDGE>(f[5], f[6], f[7], fp0, fp1, rv[7], cf, gyb + 7, gx0);
        f[5] = o5;

        if (it < NITER - 1) {
            st4(wr + wo + 0 * TWX, o0);   // publish boundary rows {0,1,6,7}
            st4(wr + wo + 1 * TWX, o1);
            st4(wr + wo + 2 * TWX, o6);
            st4(wr + wo + 3 * TWX, o7);
            f[6] = o6; f[7] = o7;
            __syncthreads();              // one barrier per sweep (ping-pong)
        } else {
            // final sweep: store valid center rows [10,58) straight from regs
            const int gxl = x0 + c - HALOX;
            if ((c >= HALOX) && (c < HALOX + TX) && (gxl <= WW - 4)) {
                const int trow0 = gyb - (y0 - HALOY);
                float* obase = ob + (ptrdiff_t)gyb * WW + gxl;
                const int gylim = HH - gyb;   // rows storable before bottom edge
#define ST_ROW(J, OJ) \
                if (trow0 + (J) >= HALOY && trow0 + (J) < HALOY + TY && (J) < gylim) \
                    st4(obase + (ptrdiff_t)(J) * WW, OJ);
                ST_ROW(0, o0) ST_ROW(1, o1) ST_ROW(2, o2) ST_ROW(3, o3)
                ST_ROW(4, o4) ST_ROW(5, o5) ST_ROW(6, o6) ST_ROW(7, o7)
#undef ST_ROW
            }
        }
    }
}

__global__ __launch_bounds__(NTHREADS, 2) void jacobi_fused(
    const float* __restrict__ g0, const float* __restrict__ rhs,
    const float* __restrict__ dx, float* __restrict__ out)
{
    // two ping-pong exchange buffers, 32 KiB exactly -> 5 blocks/CU
    __shared__ __align__(16) float lds[2 * XB];

    const int tid = (int)threadIdx.x;

    // XCD-chunked bijective swizzle: consecutive logical tiles share an XCD L2
    const int h = (int)blockIdx.x + GX * ((int)blockIdx.y + GY * (int)blockIdx.z);
    const int l = (h & (NXCD - 1)) * CHUNK + (h >> 3);
    const int tx = l % GX;
    const int t2 = l / GX;
    const int ty = t2 % GY;
    const int b  = t2 / GY;
    const int x0 = tx * TX, y0 = ty * TY;

    const float* gb = g0 + (size_t)b * HH * WW;
    const float* rb = rhs + (size_t)b * HH * WW;
    float* ob = out + (size_t)b * HH * WW;

    // per-batch coefficients (d_inv and the -cr sign folded in)
    const float t0 = 1.0f / dx[2 * b + 0], t1 = 1.0f / dx[2 * b + 1];
    const float p0 = t0 * t0, p1 = t1 * t1;
    const float d_inv = 1.0f / (-2.5f * (p0 + p1));
    Coef cf;
    cf.sH1 = -d_inv * (4.0f / 3.0f) * p0;
    cf.sH2 = -d_inv * (-1.0f / 12.0f) * p0;
    cf.sW1 = -d_inv * (4.0f / 3.0f) * p1;
    cf.sW2 = -d_inv * (-1.0f / 12.0f) * p1;

    // work item: octet oct (tile rows 2+8*oct .. 9+8*oct) x 4 cols
    const int oct = tid >> 5;          // 0..7
    const int cg  = tid & 31;          // col group 0..31
    const int c   = 4 * cg;            // tile col 0..124
    const int gx0 = x0 - HALOX + c;
    const int trow0 = 2 + 8 * oct;
    const int gyb = y0 - HALOY + trow0;

    // load octet state + scaled rhs into registers (clamp-replicate at edges)
    float4 f[8], rvv[8];
#pragma unroll
    for (int j = 0; j < 8; ++j) {
        f[j] = ld4g(gb, gyb + j, gx0);
        const float4 v = ld4g(rb, gyb + j, gx0);
        rvv[j] = make_float4(d_inv * v.x, d_inv * v.y, d_inv * v.z, d_inv * v.w);
    }

    // frozen halo rows in registers (octet 0: tile rows 0,1; octet 7: 66,67)
    float4 fz0 = {0,0,0,0}, fz1 = {0,0,0,0};
    if (oct == 0) {
        fz0 = ld4g(gb, y0 - HALOY + 0, gx0);
        fz1 = ld4g(gb, y0 - HALOY + 1, gx0);
    } else if (oct == NOCT - 1) {
        fz0 = ld4g(gb, y0 - HALOY + TWY - 2, gx0);
        fz1 = ld4g(gb, y0 - HALOY + TWY - 1, gx0);
    }

    // seed exchange buffer 0 with initial boundary rows
    st4(&lds[(oct * 4 + 0) * TWX + c], f[0]);
    st4(&lds[(oct * 4 + 1) * TWX + c], f[1]);
    st4(&lds[(oct * 4 + 2) * TWX + c], f[6]);
    st4(&lds[(oct * 4 + 3) * TWX + c], f[7]);
    __syncthreads();

    const bool interior = (x0 - HALOX >= 2) && (x0 - HALOX + TWX <= WW - 2) &&
                          (y0 - HALOY >= 2) && (y0 - HALOY + TWY <= HH - 2);
    if (interior)
        sweeps<false>(lds, f, rvv, fz0, fz1, cf, oct, c, gyb, gx0, ob, x0, y0);
    else
        sweeps<true >(lds, f, rvv, fz0, fz1, cf, oct, c, gyb, gx0, ob, x0, y0);
}

extern "C" void kernel_launch(void* const* d_in, const int* in_sizes, int n_in,
                              void* d_out, int out_size, void* d_ws, size_t ws_size,
                              hipStream_t stream) {
    const float* g0  = (const float*)d_in[0];
    const float* rhs = (const float*)d_in[1];
    const float* dx  = (const float*)d_in[2];
    float* out = (float*)d_out;

    dim3 grid(GX, GY, NB), block(NTHREADS);
    jacobi_fused<<<grid, block, 0, stream>>>(g0, rhs, dx, out);
}